// Round 1
// baseline (278.208 us; speedup 1.0000x reference)
//
#include <hip/hip_runtime.h>
#include <stdint.h>

#define B_N   65536
#define NIC   64
#define NIW   64
#define NH    128
#define NA    5
#define D2    128   // 2*NIC

// JAX >= 0.4.36 defaults jax_threefry_partitionable=True. If validation fails
// with absmax ~0.1 (mass action mismatch), flip this to 0 (legacy counter split).
#define PARTITIONABLE 1

#define P1_ROWS   128   // rows per block in policy kernel
#define P2_NCHUNK 51    // grid = 5*51 = 255 blocks (<=256 CUs, 1 block/CU via LDS)
#define P2_R      1286  // ceil(B_N / P2_NCHUNK)

__device__ __forceinline__ void threefry2x32_k042(uint32_t x0, uint32_t x1,
                                                  uint32_t& o0, uint32_t& o1) {
  const uint32_t ks0 = 0u;
  const uint32_t ks1 = 42u;
  const uint32_t ks2 = 0x1BD11BDAu ^ 0u ^ 42u;
  x0 += ks0; x1 += ks1;
#define TF_RND(r) { x0 += x1; x1 = (x1 << (r)) | (x1 >> (32 - (r))); x1 ^= x0; }
  TF_RND(13) TF_RND(15) TF_RND(26) TF_RND(6)
  x0 += ks1; x1 += ks2 + 1u;
  TF_RND(17) TF_RND(29) TF_RND(16) TF_RND(24)
  x0 += ks2; x1 += ks0 + 2u;
  TF_RND(13) TF_RND(15) TF_RND(26) TF_RND(6)
  x0 += ks0; x1 += ks1 + 3u;
  TF_RND(17) TF_RND(29) TF_RND(16) TF_RND(24)
  x0 += ks1; x1 += ks2 + 4u;
  TF_RND(13) TF_RND(15) TF_RND(26) TF_RND(6)
  x0 += ks2; x1 += ks0 + 5u;
#undef TF_RND
  o0 = x0; o1 = x1;
}

// Gumbel sample for flat index idx of the (B, NA) draw, matching
// -log(-log(uniform(key, tiny, 1))) computed in f32 by the reference.
__device__ __forceinline__ float gumbel_at(uint32_t idx) {
  uint32_t bits;
#if PARTITIONABLE
  uint32_t a, b;
  threefry2x32_k042(0u, idx, a, b);
  bits = a ^ b;
#else
  const uint32_t HALF = (uint32_t)(B_N * NA) / 2u;
  uint32_t a, b;
  if (idx < HALF) { threefry2x32_k042(idx, idx + HALF, a, b); bits = a; }
  else            { threefry2x32_k042(idx - HALF, idx, a, b); bits = b; }
#endif
  const float f = __uint_as_float((bits >> 9) | 0x3f800000u) - 1.0f;
  const double u = (f == 0.0f) ? (double)0x1p-126 : (double)f;
  const float nl = (float)(-log(u));           // f32-rounded inner log, like ref
  const float g  = (float)(-log((double)nl));  // f32-rounded outer log
  return g;
}

// ---------------- Phase 1: policy MLP + categorical sample + wemb gather ----
__global__ __launch_bounds__(512, 1) void policy_kernel(
    const int* __restrict__ x, const int* __restrict__ y,
    const float* __restrict__ cemb, const float* __restrict__ wemb,
    const float* __restrict__ Wp1, const float* __restrict__ bp1,
    const float* __restrict__ Wp2, const float* __restrict__ bp2,
    float* __restrict__ out_wemb, int* __restrict__ action) {
  __shared__ __align__(16) float sW1[D2 * NH];      // 64 KB
  __shared__ __align__(16) float sW2[NH * NA];      // 2.5 KB
  __shared__ __align__(16) float sb1[NH];
  __shared__ __align__(16) float sb2[8];
  __shared__ __align__(16) float sC[8][D2];         // per-wave activations

  const int tid = threadIdx.x;
  {
    const float4* src = (const float4*)Wp1;
    float4* dst = (float4*)sW1;
#pragma unroll
    for (int i = 0; i < 8; i++) dst[tid + i * 512] = src[tid + i * 512];
    if (tid < (NH * NA) / 4) ((float4*)sW2)[tid] = ((const float4*)Wp2)[tid];
    if (tid < NH / 4)        ((float4*)sb1)[tid] = ((const float4*)bp1)[tid];
    if (tid < NA)            sb2[tid] = bp2[tid];
  }
  __syncthreads();

  const int wave = tid >> 6, lane = tid & 63;
  const int rowBase = blockIdx.x * P1_ROWS;

#pragma unroll 1
  for (int it = 0; it < P1_ROWS / 8; it++) {
    const int row = rowBase + wave + it * 8;
    const int x0 = x[row * 2], x1 = x[row * 2 + 1];
    // gather char embeddings: lane l holds cembs[l] and cembs[64+l]
    sC[wave][lane]       = cemb[x0 * NIC + lane];
    sC[wave][NIC + lane] = cemb[x1 * NIC + lane];
    // (same-wave LDS ops are in-order; no barrier needed)

    float acc0 = sb1[lane], acc1 = sb1[64 + lane];
#pragma unroll
    for (int k = 0; k < D2; k += 4) {
      const float4 c4 = *(const float4*)&sC[wave][k];
      acc0 = fmaf(c4.x, sW1[(k + 0) * NH + lane], acc0);
      acc0 = fmaf(c4.y, sW1[(k + 1) * NH + lane], acc0);
      acc0 = fmaf(c4.z, sW1[(k + 2) * NH + lane], acc0);
      acc0 = fmaf(c4.w, sW1[(k + 3) * NH + lane], acc0);
      acc1 = fmaf(c4.x, sW1[(k + 0) * NH + 64 + lane], acc1);
      acc1 = fmaf(c4.y, sW1[(k + 1) * NH + 64 + lane], acc1);
      acc1 = fmaf(c4.z, sW1[(k + 2) * NH + 64 + lane], acc1);
      acc1 = fmaf(c4.w, sW1[(k + 3) * NH + 64 + lane], acc1);
    }
    const float h0 = fmaxf(acc0, 0.0f), h1 = fmaxf(acc1, 0.0f);

    float p[NA];
#pragma unroll
    for (int a = 0; a < NA; a++)
      p[a] = fmaf(h0, sW2[lane * NA + a], h1 * sW2[(64 + lane) * NA + a]);
#pragma unroll
    for (int off = 32; off > 0; off >>= 1) {
#pragma unroll
      for (int a = 0; a < NA; a++) p[a] += __shfl_xor(p[a], off);
    }

    float score = -3.0e38f;
    if (lane < NA) {
      const float logit = p[lane] + sb2[lane];
      score = gumbel_at((uint32_t)(row * NA + lane)) + logit;  // f32 add = ref
    }
    int best = 0;
    float bs = __shfl(score, 0);
#pragma unroll
    for (int a = 1; a < NA; a++) {
      const float s = __shfl(score, a);
      if (s > bs) { bs = s; best = a; }  // strict >: keep first max, like argmax
    }
    if (lane == 0) action[row] = best;

    // word-embedding output half
    out_wemb[row * NIW + lane] = wemb[(size_t)y[row] * NIW + lane];
  }
}

// ---------------- Phase 2: selected-expert MLP, bucketed by action ----------
__global__ __launch_bounds__(512, 1) void expert_kernel(
    const int* __restrict__ x, const float* __restrict__ cemb,
    const float* __restrict__ We1, const float* __restrict__ be1,
    const float* __restrict__ We2, const float* __restrict__ be2,
    const int* __restrict__ action, float* __restrict__ out) {
  __shared__ __align__(16) float sW1[D2 * NH];   // 64 KB  We1[a]
  __shared__ __align__(16) float sW2[NH * NIW];  // 32 KB  We2[a]
  __shared__ __align__(16) float sb1[NH];
  __shared__ __align__(16) float sb2[NIW];
  __shared__ __align__(16) float sC[8][D2];
  __shared__ __align__(16) float sH[8][NH];
  __shared__ int sList[P2_R];
  __shared__ int sCount;

  const int tid = threadIdx.x;
  const int a = blockIdx.x % NA;
  const int chunk = blockIdx.x / NA;
  const int rowBeg = chunk * P2_R;
  const int rowEnd = (rowBeg + P2_R < B_N) ? rowBeg + P2_R : B_N;

  if (tid == 0) sCount = 0;
  __syncthreads();
  for (int r = rowBeg + tid; r < rowEnd; r += 512)
    if (action[r] == a) sList[atomicAdd(&sCount, 1)] = r;
  __syncthreads();
  const int cnt = sCount;
  if (cnt == 0) return;

  {
    const float4* s1 = (const float4*)(We1 + (size_t)a * D2 * NH);
    const float4* s2 = (const float4*)(We2 + (size_t)a * NH * NIW);
#pragma unroll
    for (int i = 0; i < 8; i++) ((float4*)sW1)[tid + i * 512] = s1[tid + i * 512];
#pragma unroll
    for (int i = 0; i < 4; i++) ((float4*)sW2)[tid + i * 512] = s2[tid + i * 512];
    if (tid < NH / 4)  ((float4*)sb1)[tid] = ((const float4*)(be1 + a * NH))[tid];
    if (tid < NIW / 4) ((float4*)sb2)[tid] = ((const float4*)(be2 + a * NIW))[tid];
  }
  __syncthreads();

  const int wave = tid >> 6, lane = tid & 63;
#pragma unroll 1
  for (int idx = wave; idx < cnt; idx += 8) {
    const int row = sList[idx];
    const int x0 = x[row * 2], x1 = x[row * 2 + 1];
    sC[wave][lane]       = cemb[x0 * NIC + lane];
    sC[wave][NIC + lane] = cemb[x1 * NIC + lane];

    float acc0 = sb1[lane], acc1 = sb1[64 + lane];
#pragma unroll
    for (int k = 0; k < D2; k += 4) {
      const float4 c4 = *(const float4*)&sC[wave][k];
      acc0 = fmaf(c4.x, sW1[(k + 0) * NH + lane], acc0);
      acc0 = fmaf(c4.y, sW1[(k + 1) * NH + lane], acc0);
      acc0 = fmaf(c4.z, sW1[(k + 2) * NH + lane], acc0);
      acc0 = fmaf(c4.w, sW1[(k + 3) * NH + lane], acc0);
      acc1 = fmaf(c4.x, sW1[(k + 0) * NH + 64 + lane], acc1);
      acc1 = fmaf(c4.y, sW1[(k + 1) * NH + 64 + lane], acc1);
      acc1 = fmaf(c4.z, sW1[(k + 2) * NH + 64 + lane], acc1);
      acc1 = fmaf(c4.w, sW1[(k + 3) * NH + 64 + lane], acc1);
    }
    sH[wave][lane]      = fmaxf(acc0, 0.0f);
    sH[wave][64 + lane] = fmaxf(acc1, 0.0f);

    float oA = sb2[lane], oB = 0.0f, oC = 0.0f, oD = 0.0f;
#pragma unroll
    for (int j = 0; j < NH; j += 4) {
      const float4 h4 = *(const float4*)&sH[wave][j];
      oA = fmaf(h4.x, sW2[(j + 0) * NIW + lane], oA);
      oB = fmaf(h4.y, sW2[(j + 1) * NIW + lane], oB);
      oC = fmaf(h4.z, sW2[(j + 2) * NIW + lane], oC);
      oD = fmaf(h4.w, sW2[(j + 3) * NIW + lane], oD);
    }
    out[row * NIW + lane] = (oA + oB) + (oC + oD);
  }
}

extern "C" void kernel_launch(void* const* d_in, const int* in_sizes, int n_in,
                              void* d_out, int out_size, void* d_ws, size_t ws_size,
                              hipStream_t stream) {
  const int*   x    = (const int*)d_in[0];
  const int*   y    = (const int*)d_in[1];
  const float* cemb = (const float*)d_in[2];
  const float* wemb = (const float*)d_in[3];
  const float* Wp1  = (const float*)d_in[4];
  const float* bp1  = (const float*)d_in[5];
  const float* Wp2  = (const float*)d_in[6];
  const float* bp2  = (const float*)d_in[7];
  const float* We1  = (const float*)d_in[8];
  const float* be1  = (const float*)d_in[9];
  const float* We2  = (const float*)d_in[10];
  const float* be2  = (const float*)d_in[11];

  float* out      = (float*)d_out;
  float* out_wemb = out + (size_t)B_N * NIW;
  int*   action   = (int*)d_ws;   // B_N ints

  policy_kernel<<<B_N / P1_ROWS, 512, 0, stream>>>(
      x, y, cemb, wemb, Wp1, bp1, Wp2, bp2, out_wemb, action);
  expert_kernel<<<NA * P2_NCHUNK, 512, 0, stream>>>(
      x, cemb, We1, be1, We2, be2, action, out);
}

// Round 2
// 73.003 us; speedup vs baseline: 3.8109x; 3.8109x over previous
//
#include <hip/hip_runtime.h>
#include <stdint.h>

#define B_N   65536
#define NIC   64
#define NIW   64
#define NH    128
#define NA    5
#define D2    128   // 2*NIC

#define PARTITIONABLE 1

#define P2_NCHUNK 51
#define P2_R      1286  // ceil(B_N / P2_NCHUNK)

typedef __attribute__((ext_vector_type(8))) short short8;
typedef __attribute__((ext_vector_type(4))) float f32x4;

__device__ __forceinline__ ushort f2bf(float f) {
  uint32_t u = __float_as_uint(f);
  uint32_t r = (u + 0x7FFFu + ((u >> 16) & 1u)) >> 16;  // RNE
  return (ushort)r;
}

__device__ __forceinline__ void threefry2x32_k042(uint32_t x0, uint32_t x1,
                                                  uint32_t& o0, uint32_t& o1) {
  const uint32_t ks0 = 0u;
  const uint32_t ks1 = 42u;
  const uint32_t ks2 = 0x1BD11BDAu ^ 0u ^ 42u;
  x0 += ks0; x1 += ks1;
#define TF_RND(r) { x0 += x1; x1 = (x1 << (r)) | (x1 >> (32 - (r))); x1 ^= x0; }
  TF_RND(13) TF_RND(15) TF_RND(26) TF_RND(6)
  x0 += ks1; x1 += ks2 + 1u;
  TF_RND(17) TF_RND(29) TF_RND(16) TF_RND(24)
  x0 += ks2; x1 += ks0 + 2u;
  TF_RND(13) TF_RND(15) TF_RND(26) TF_RND(6)
  x0 += ks0; x1 += ks1 + 3u;
  TF_RND(17) TF_RND(29) TF_RND(16) TF_RND(24)
  x0 += ks1; x1 += ks2 + 4u;
  TF_RND(13) TF_RND(15) TF_RND(26) TF_RND(6)
  x0 += ks2; x1 += ks0 + 5u;
#undef TF_RND
  o0 = x0; o1 = x1;
}

__device__ __forceinline__ float gumbel_at(uint32_t idx) {
  uint32_t bits;
#if PARTITIONABLE
  uint32_t a, b;
  threefry2x32_k042(0u, idx, a, b);
  bits = a ^ b;
#else
  const uint32_t HALF = (uint32_t)(B_N * NA) / 2u;
  uint32_t a, b;
  if (idx < HALF) { threefry2x32_k042(idx, idx + HALF, a, b); bits = a; }
  else            { threefry2x32_k042(idx - HALF, idx, a, b); bits = b; }
#endif
  const float f = __uint_as_float((bits >> 9) | 0x3f800000u) - 1.0f;
  const double u = (f == 0.0f) ? (double)0x1p-126 : (double)f;
  const float nl = (float)(-log(u));
  const float g  = (float)(-log((double)nl));
  return g;
}

// ---------------- Phase 1: policy MLP (f32) + categorical + wemb gather -----
__global__ __launch_bounds__(512, 1) void policy_kernel(
    const int* __restrict__ x, const int* __restrict__ y,
    const float* __restrict__ cemb, const float* __restrict__ wemb,
    const float* __restrict__ Wp1, const float* __restrict__ bp1,
    const float* __restrict__ Wp2, const float* __restrict__ bp2,
    float* __restrict__ out_wemb, int* __restrict__ action) {
  __shared__ __align__(16) float sW[D2 * NH];       // Wp1 [k][n], 64 KB
  __shared__ __align__(16) float sCH[128][132];     // cembs (cols=k) then h (cols=n)
  __shared__ __align__(16) float sW2t[NA][NH];      // Wp2 transposed [a][k]
  __shared__ __align__(16) float sb1[NH];
  __shared__ __align__(16) float sScore[128][6];

  const int tid = threadIdx.x;
  const int base = blockIdx.x * 128;

  // stage Wp1 (coalesced), bp1, Wp2^T
  {
    const float4* src = (const float4*)Wp1;
    float4* dst = (float4*)sW;
#pragma unroll
    for (int i = 0; i < 8; i++) dst[tid + i * 512] = src[tid + i * 512];
    if (tid < NH) sb1[tid] = bp1[tid];
    if (tid < NA * 32) {
      const int a = tid >> 5, k0 = (tid & 31) * 4;
#pragma unroll
      for (int j = 0; j < 4; j++) sW2t[a][k0 + j] = Wp2[(k0 + j) * NA + a];
    }
  }
  // gather char embeddings: thread -> (row, quarter)
  {
    const int row = tid >> 2, q = tid & 3;
    const int xi = x[(base + row) * 2 + (q >> 1)];
    const float4* src = (const float4*)(cemb + (size_t)xi * NIC + (q & 1) * 32);
    float4* dst = (float4*)&sCH[row][q * 32];
#pragma unroll
    for (int j = 0; j < 8; j++) dst[j] = src[j];
  }
  __syncthreads();

  const int wave = tid >> 6, lane = tid & 63;
  // L1: wave handles rows [16*wave, 16*wave+16), two groups of 8.
  // lane covers output channels n = 2*lane, 2*lane+1.
#pragma unroll 1
  for (int g = 0; g < 2; ++g) {
    const int r0 = wave * 16 + g * 8;
    float acc[8][2];
    const float2 b2 = *(const float2*)&sb1[2 * lane];
#pragma unroll
    for (int r = 0; r < 8; r++) { acc[r][0] = b2.x; acc[r][1] = b2.y; }
#pragma unroll 2
    for (int k = 0; k < D2; k += 4) {
      float4 c[8];
#pragma unroll
      for (int r = 0; r < 8; r++) c[r] = *(const float4*)&sCH[r0 + r][k];
#pragma unroll
      for (int kk = 0; kk < 4; kk++) {
        const float2 w = *(const float2*)&sW[(k + kk) * NH + 2 * lane];
#pragma unroll
        for (int r = 0; r < 8; r++) {
          const float cv = ((const float*)&c[r])[kk];
          acc[r][0] = fmaf(cv, w.x, acc[r][0]);
          acc[r][1] = fmaf(cv, w.y, acc[r][1]);
        }
      }
    }
    // relu + write h back into sCH (cols become n); rows are wave-private.
#pragma unroll
    for (int r = 0; r < 8; r++) {
      float2 h2;
      h2.x = fmaxf(acc[r][0], 0.0f);
      h2.y = fmaxf(acc[r][1], 0.0f);
      *(float2*)&sCH[r0 + r][2 * lane] = h2;
    }
  }
  __syncthreads();

  // logits + gumbel scores, parallel over (row, a) pairs
#pragma unroll 1
  for (int p = tid; p < 128 * NA; p += 512) {
    const int row = p / NA, a = p - NA * row;
    float s0 = 0.f, s1 = 0.f, s2 = 0.f, s3 = 0.f;
#pragma unroll 4
    for (int k = 0; k < NH; k += 4) {
      const float4 h4 = *(const float4*)&sCH[row][k];
      const float4 w4 = *(const float4*)&sW2t[a][k];
      s0 = fmaf(h4.x, w4.x, s0);
      s1 = fmaf(h4.y, w4.y, s1);
      s2 = fmaf(h4.z, w4.z, s2);
      s3 = fmaf(h4.w, w4.w, s3);
    }
    const float logit = ((s0 + s1) + (s2 + s3)) + bp2[a];
    sScore[row][a] = gumbel_at((uint32_t)((base + row) * NA + a)) + logit;
  }
  __syncthreads();

  if (tid < 128) {
    int best = 0;
    float bs = sScore[tid][0];
#pragma unroll
    for (int a = 1; a < NA; a++) {
      const float s = sScore[tid][a];
      if (s > bs) { bs = s; best = a; }
    }
    action[base + tid] = best;
  }

  // word-embedding gather (independent output half)
#pragma unroll 1
  for (int i = tid; i < 128 * 16; i += 512) {
    const int row = i >> 4, seg = i & 15;
    ((float4*)out_wemb)[(size_t)(base + row) * 16 + seg] =
        ((const float4*)wemb)[(size_t)y[base + row] * 16 + seg];
  }
}

// ---------------- Phase 2: selected-expert MLP via bf16 MFMA ----------------
// Fragment-order LDS layout: block fb holds 64 lanes x 8 bf16 (16 B) each.
// A-frag (16x32): lane = row + 16*((k%32)/8), elem j -> k = 32*kt + 8*((lane>>4)) + j
// B-frag (32x16): lane = col + 16*((k%32)/8)
__global__ __launch_bounds__(512, 1) void expert_kernel(
    const int* __restrict__ x, const float* __restrict__ cemb,
    const float* __restrict__ We1, const float* __restrict__ be1,
    const float* __restrict__ We2, const float* __restrict__ be2,
    const int* __restrict__ action, float* __restrict__ out) {
  __shared__ __align__(16) ushort sW1[32 * 512];   // 8 ct x 4 kt frag blocks, 32 KB
  __shared__ __align__(16) ushort sW2[16 * 512];   // 4 ot x 4 kt frag blocks, 16 KB
  __shared__ __align__(16) ushort sCt[8][4 * 512]; // per-wave A tiles, 32 KB
  __shared__ __align__(16) ushort sHt[8][4 * 512]; // per-wave h tiles, 32 KB
  __shared__ __align__(16) float sbe1[NH];
  __shared__ __align__(16) float sbe2[NIW];
  __shared__ int sList[P2_R];
  __shared__ int sCount;

  const int tid = threadIdx.x;
  const int a = blockIdx.x % NA;
  const int chunk = blockIdx.x / NA;
  const int rowBeg = chunk * P2_R;
  const int rowEnd = (rowBeg + P2_R < B_N) ? rowBeg + P2_R : B_N;

  if (tid == 0) sCount = 0;
  __syncthreads();

  // compaction
  for (int r = rowBeg + tid; r < rowEnd; r += 512)
    if (action[r] == a) sList[atomicAdd(&sCount, 1)] = r;

  // We1[a] (k,n)->fragment-order bf16; thread: n = tid&127, kt = tid>>7
  {
    const float* W1g = We1 + (size_t)a * D2 * NH;
    const int n = tid & 127, q = tid >> 7;
    const int fb = (n >> 4) * 4 + q;
    const int c16 = n & 15;
#pragma unroll
    for (int grp = 0; grp < 4; grp++) {
      short8 pk;
#pragma unroll
      for (int j = 0; j < 8; j++) {
        const int k = 32 * q + 8 * grp + j;
        pk[j] = (short)f2bf(W1g[k * NH + n]);
      }
      *(short8*)&sW1[fb * 512 + (c16 + 16 * grp) * 8] = pk;
    }
    if (tid < NH) sbe1[tid] = be1[a * NH + tid];
    if (tid < NIW) sbe2[tid] = be2[a * NIW + tid];
  }
  // We2[a] (h,o)->fragment-order; thread: o = tid&63, hq = tid>>6 (16 h each)
  {
    const float* W2g = We2 + (size_t)a * NH * NIW;
    const int o = tid & 63, hq = tid >> 6;  // hq 0..7
    const int fb = (o >> 4) * 4 + (hq >> 1);
    const int c16 = o & 15;
#pragma unroll
    for (int g2 = 0; g2 < 2; g2++) {
      const int grp = (hq & 1) * 2 + g2;
      short8 pk;
#pragma unroll
      for (int j = 0; j < 8; j++) {
        const int h = 16 * hq + 8 * g2 + j;
        pk[j] = (short)f2bf(W2g[h * NIW + o]);
      }
      *(short8*)&sW2[fb * 512 + (c16 + 16 * grp) * 8] = pk;
    }
  }
  __syncthreads();

  const int cnt = sCount;
  if (cnt == 0) return;

  const int wave = tid >> 6, lane = tid & 63;
  const int rowb = (lane >> 4) * 4;
  ushort* myCt = sCt[wave];
  ushort* myHt = sHt[wave];

#pragma unroll 1
  for (int t16 = wave * 16; t16 < cnt; t16 += 128) {
    // gather 16 rows of cembs -> bf16 A-frag layout
    {
      const int rt = lane >> 2, q = lane & 3;
      int li = t16 + rt;
      const int g = sList[(li < cnt) ? li : 0];
      const int xi = x[2 * g + (q >> 1)];
      const float4* src = (const float4*)(cemb + (size_t)xi * NIC + (q & 1) * 32);
#pragma unroll
      for (int grp = 0; grp < 4; grp++) {
        const float4 aa = src[2 * grp], bb = src[2 * grp + 1];
        short8 pk;
        pk[0] = (short)f2bf(aa.x); pk[1] = (short)f2bf(aa.y);
        pk[2] = (short)f2bf(aa.z); pk[3] = (short)f2bf(aa.w);
        pk[4] = (short)f2bf(bb.x); pk[5] = (short)f2bf(bb.y);
        pk[6] = (short)f2bf(bb.z); pk[7] = (short)f2bf(bb.w);
        *(short8*)&myCt[q * 512 + (rt + 16 * grp) * 8] = pk;
      }
    }

    // L1: [16x128] @ [128x128] -> relu -> Ht (bf16, A-frag layout)
    short8 A[4];
#pragma unroll
    for (int kt = 0; kt < 4; kt++) A[kt] = *(const short8*)&myCt[kt * 512 + lane * 8];
#pragma unroll
    for (int ct = 0; ct < 8; ct++) {
      const int n = ct * 16 + (lane & 15);
      const float bv = sbe1[n];
      f32x4 acc = {bv, bv, bv, bv};
#pragma unroll
      for (int kt = 0; kt < 4; kt++) {
        const short8 Bf = *(const short8*)&sW1[(ct * 4 + kt) * 512 + lane * 8];
        acc = __builtin_amdgcn_mfma_f32_16x16x32_bf16(A[kt], Bf, acc, 0, 0, 0);
      }
      const int kt2 = n >> 5, grp2 = (n & 31) >> 3, j2 = n & 7;
#pragma unroll
      for (int r = 0; r < 4; r++) {
        const float hv = fmaxf(acc[r], 0.0f);
        myHt[kt2 * 512 + ((rowb + r) + 16 * grp2) * 8 + j2] = f2bf(hv);
      }
    }

    // L2: [16x128] @ [128x64] + be2 -> out (masked scatter)
    short8 A2[4];
#pragma unroll
    for (int kt = 0; kt < 4; kt++) A2[kt] = *(const short8*)&myHt[kt * 512 + lane * 8];
    int gr4[4];
#pragma unroll
    for (int r = 0; r < 4; r++) {
      const int li2 = t16 + rowb + r;
      gr4[r] = (li2 < cnt) ? sList[li2] : -1;
    }
#pragma unroll
    for (int ot = 0; ot < 4; ot++) {
      const int o = ot * 16 + (lane & 15);
      const float bv = sbe2[o];
      f32x4 o4 = {bv, bv, bv, bv};
#pragma unroll
      for (int kt = 0; kt < 4; kt++) {
        const short8 Bf = *(const short8*)&sW2[(ot * 4 + kt) * 512 + lane * 8];
        o4 = __builtin_amdgcn_mfma_f32_16x16x32_bf16(A2[kt], Bf, o4, 0, 0, 0);
      }
#pragma unroll
      for (int r = 0; r < 4; r++) {
        if (gr4[r] >= 0) out[(size_t)gr4[r] * NIW + o] = o4[r];
      }
    }
  }
}

extern "C" void kernel_launch(void* const* d_in, const int* in_sizes, int n_in,
                              void* d_out, int out_size, void* d_ws, size_t ws_size,
                              hipStream_t stream) {
  const int*   x    = (const int*)d_in[0];
  const int*   y    = (const int*)d_in[1];
  const float* cemb = (const float*)d_in[2];
  const float* wemb = (const float*)d_in[3];
  const float* Wp1  = (const float*)d_in[4];
  const float* bp1  = (const float*)d_in[5];
  const float* Wp2  = (const float*)d_in[6];
  const float* bp2  = (const float*)d_in[7];
  const float* We1  = (const float*)d_in[8];
  const float* be1  = (const float*)d_in[9];
  const float* We2  = (const float*)d_in[10];
  const float* be2  = (const float*)d_in[11];

  float* out      = (float*)d_out;
  float* out_wemb = out + (size_t)B_N * NIW;
  int*   action   = (int*)d_ws;   // B_N ints

  policy_kernel<<<B_N / 128, 512, 0, stream>>>(
      x, y, cemb, wemb, Wp1, bp1, Wp2, bp2, out_wemb, action);
  expert_kernel<<<NA * P2_NCHUNK, 512, 0, stream>>>(
      x, cemb, We1, be1, We2, be2, action, out);
}

// Round 3
// 50.731 us; speedup vs baseline: 5.4840x; 1.4390x over previous
//
#include <hip/hip_runtime.h>
#include <stdint.h>

#define B_N   65536
#define NIC   64
#define NIW   64
#define NH    128
#define NA    5
#define D2    128   // 2*NIC

#define PARTITIONABLE 1

#define P2_NCHUNK 51
#define P2_R      1286  // ceil(B_N / P2_NCHUNK)

typedef __attribute__((ext_vector_type(8))) short short8;
typedef __attribute__((ext_vector_type(4))) float f32x4;

__device__ __forceinline__ ushort f2bf(float f) {
  uint32_t u = __float_as_uint(f);
  uint32_t r = (u + 0x7FFFu + ((u >> 16) & 1u)) >> 16;  // RNE
  return (ushort)r;
}

// split f into hi+lo bf16 (hi = RNE(f), lo = RNE(f - hi)); hi+lo ~ 17-bit accurate
__device__ __forceinline__ void split2(float f, ushort& h, ushort& l) {
  h = f2bf(f);
  l = f2bf(f - __uint_as_float(((uint32_t)h) << 16));
}

__device__ __forceinline__ void threefry2x32_k042(uint32_t x0, uint32_t x1,
                                                  uint32_t& o0, uint32_t& o1) {
  const uint32_t ks0 = 0u;
  const uint32_t ks1 = 42u;
  const uint32_t ks2 = 0x1BD11BDAu ^ 0u ^ 42u;
  x0 += ks0; x1 += ks1;
#define TF_RND(r) { x0 += x1; x1 = (x1 << (r)) | (x1 >> (32 - (r))); x1 ^= x0; }
  TF_RND(13) TF_RND(15) TF_RND(26) TF_RND(6)
  x0 += ks1; x1 += ks2 + 1u;
  TF_RND(17) TF_RND(29) TF_RND(16) TF_RND(24)
  x0 += ks2; x1 += ks0 + 2u;
  TF_RND(13) TF_RND(15) TF_RND(26) TF_RND(6)
  x0 += ks0; x1 += ks1 + 3u;
  TF_RND(17) TF_RND(29) TF_RND(16) TF_RND(24)
  x0 += ks1; x1 += ks2 + 4u;
  TF_RND(13) TF_RND(15) TF_RND(26) TF_RND(6)
  x0 += ks2; x1 += ks0 + 5u;
#undef TF_RND
  o0 = x0; o1 = x1;
}

__device__ __forceinline__ float gumbel_at(uint32_t idx) {
  uint32_t bits;
#if PARTITIONABLE
  uint32_t a, b;
  threefry2x32_k042(0u, idx, a, b);
  bits = a ^ b;
#else
  const uint32_t HALF = (uint32_t)(B_N * NA) / 2u;
  uint32_t a, b;
  if (idx < HALF) { threefry2x32_k042(idx, idx + HALF, a, b); bits = a; }
  else            { threefry2x32_k042(idx - HALF, idx, a, b); bits = b; }
#endif
  const float f = __uint_as_float((bits >> 9) | 0x3f800000u) - 1.0f;
  const double u = (f == 0.0f) ? (double)0x1p-126 : (double)f;
  const float nl = (float)(-log(u));
  const float g  = (float)(-log((double)nl));
  return g;
}

// ---------------- Phase 1: policy MLP L1 via split-bf16 MFMA ----------------
// Fragment layouts identical to the (verified) expert kernel:
//   A-frag: row = lane&15, k = 32*kt + 8*(lane>>4) + j
//   B-frag: col = ct*16 + (lane&15), k = 32*kt + 8*(lane>>4) + j
//   C/D   : col = lane&15 (+16*ct), row = (lane>>4)*4 + r
__global__ __launch_bounds__(512, 1) void policy_kernel(
    const int* __restrict__ x, const int* __restrict__ y,
    const float* __restrict__ cemb, const float* __restrict__ wemb,
    const float* __restrict__ Wp1, const float* __restrict__ bp1,
    const float* __restrict__ Wp2, const float* __restrict__ bp2,
    float* __restrict__ out_wemb, int* __restrict__ action) {
  __shared__ __align__(16) ushort sW1h[32 * 512];   // 32 KB Wp1 hi frags
  __shared__ __align__(16) ushort sW1l[32 * 512];   // 32 KB Wp1 lo frags
  __shared__ __align__(16) float sCH[128][132];     // h (f32), 67.6 KB
  __shared__ __align__(16) float sW2t[NA][NH];      // Wp2^T
  __shared__ __align__(16) float sb1[NH];
  __shared__ __align__(16) float sScore[128][6];

  const int tid = threadIdx.x;
  const int base = blockIdx.x * 128;

  // stage Wp1 hi/lo in fragment order; thread: n = tid&127, kt = tid>>7
  {
    const int n = tid & 127, q = tid >> 7;
    const int fb = (n >> 4) * 4 + q;
    const int c16 = n & 15;
#pragma unroll
    for (int grp = 0; grp < 4; grp++) {
      short8 ph, pl;
#pragma unroll
      for (int j = 0; j < 8; j++) {
        const int k = 32 * q + 8 * grp + j;
        ushort hh, ll;
        split2(Wp1[k * NH + n], hh, ll);
        ph[j] = (short)hh;
        pl[j] = (short)ll;
      }
      *(short8*)&sW1h[fb * 512 + (c16 + 16 * grp) * 8] = ph;
      *(short8*)&sW1l[fb * 512 + (c16 + 16 * grp) * 8] = pl;
    }
    if (tid < NH) sb1[tid] = bp1[tid];
    if (tid < NA * 32) {
      const int a = tid >> 5, k0 = (tid & 31) * 4;
#pragma unroll
      for (int j = 0; j < 4; j++) sW2t[a][k0 + j] = Wp2[(k0 + j) * NA + a];
    }
  }

  const int wave = tid >> 6, lane = tid & 63;
  const int c16 = lane & 15, h2 = lane >> 4;

  // Build A-fragments (hi/lo) in registers from global cemb gathers.
  const int grow = base + wave * 16 + c16;   // this lane's A-row
  const int xi0 = x[grow * 2], xi1 = x[grow * 2 + 1];
  short8 Ah[4], Al[4];
#pragma unroll
  for (int kt = 0; kt < 4; kt++) {
    const int xi = (kt < 2) ? xi0 : xi1;
    const float* src = cemb + (size_t)xi * NIC + (kt & 1) * 32 + h2 * 8;
    const float4 aa = *(const float4*)src;
    const float4 bb = *(const float4*)(src + 4);
    ushort hh, ll;
    short8 ph, pl;
    split2(aa.x, hh, ll); ph[0] = (short)hh; pl[0] = (short)ll;
    split2(aa.y, hh, ll); ph[1] = (short)hh; pl[1] = (short)ll;
    split2(aa.z, hh, ll); ph[2] = (short)hh; pl[2] = (short)ll;
    split2(aa.w, hh, ll); ph[3] = (short)hh; pl[3] = (short)ll;
    split2(bb.x, hh, ll); ph[4] = (short)hh; pl[4] = (short)ll;
    split2(bb.y, hh, ll); ph[5] = (short)hh; pl[5] = (short)ll;
    split2(bb.z, hh, ll); ph[6] = (short)hh; pl[6] = (short)ll;
    split2(bb.w, hh, ll); ph[7] = (short)hh; pl[7] = (short)ll;
    Ah[kt] = ph;
    Al[kt] = pl;
  }
  __syncthreads();

  // L1: h = relu(C @ Wp1 + b), 4-term split-bf16 MFMA (~f32 precision)
  f32x4 acc[8];
#pragma unroll
  for (int ct = 0; ct < 8; ct++) {
    const float bv = sb1[ct * 16 + c16];
    acc[ct] = (f32x4){bv, bv, bv, bv};
  }
#pragma unroll
  for (int kt = 0; kt < 4; kt++) {
#pragma unroll
    for (int ct = 0; ct < 8; ct++) {
      const short8 Bh = *(const short8*)&sW1h[(ct * 4 + kt) * 512 + lane * 8];
      const short8 Bl = *(const short8*)&sW1l[(ct * 4 + kt) * 512 + lane * 8];
      acc[ct] = __builtin_amdgcn_mfma_f32_16x16x32_bf16(Ah[kt], Bh, acc[ct], 0, 0, 0);
      acc[ct] = __builtin_amdgcn_mfma_f32_16x16x32_bf16(Al[kt], Bh, acc[ct], 0, 0, 0);
      acc[ct] = __builtin_amdgcn_mfma_f32_16x16x32_bf16(Ah[kt], Bl, acc[ct], 0, 0, 0);
      acc[ct] = __builtin_amdgcn_mfma_f32_16x16x32_bf16(Al[kt], Bl, acc[ct], 0, 0, 0);
    }
  }
  // write h (f32) to sCH; D layout: row = (lane>>4)*4 + r, col = ct*16 + c16
  {
    const int rowb = wave * 16 + h2 * 4;
#pragma unroll
    for (int ct = 0; ct < 8; ct++) {
      const int n = ct * 16 + c16;
#pragma unroll
      for (int r = 0; r < 4; r++)
        sCH[rowb + r][n] = fmaxf(acc[ct][r], 0.0f);
    }
  }
  __syncthreads();

  // logits + gumbel scores, parallel over (row, a) pairs  [proven epilogue]
#pragma unroll 1
  for (int p = tid; p < 128 * NA; p += 512) {
    const int row = p / NA, a = p - NA * row;
    float s0 = 0.f, s1 = 0.f, s2 = 0.f, s3 = 0.f;
#pragma unroll 4
    for (int k = 0; k < NH; k += 4) {
      const float4 h4 = *(const float4*)&sCH[row][k];
      const float4 w4 = *(const float4*)&sW2t[a][k];
      s0 = fmaf(h4.x, w4.x, s0);
      s1 = fmaf(h4.y, w4.y, s1);
      s2 = fmaf(h4.z, w4.z, s2);
      s3 = fmaf(h4.w, w4.w, s3);
    }
    const float logit = ((s0 + s1) + (s2 + s3)) + bp2[a];
    sScore[row][a] = gumbel_at((uint32_t)((base + row) * NA + a)) + logit;
  }
  __syncthreads();

  if (tid < 128) {
    int best = 0;
    float bs = sScore[tid][0];
#pragma unroll
    for (int a = 1; a < NA; a++) {
      const float s = sScore[tid][a];
      if (s > bs) { bs = s; best = a; }
    }
    action[base + tid] = best;
  }

  // word-embedding gather (independent output half)
#pragma unroll 1
  for (int i = tid; i < 128 * 16; i += 512) {
    const int row = i >> 4, seg = i & 15;
    ((float4*)out_wemb)[(size_t)(base + row) * 16 + seg] =
        ((const float4*)wemb)[(size_t)y[base + row] * 16 + seg];
  }
}

// ---------------- Phase 2: selected-expert MLP via bf16 MFMA (unchanged) ----
__global__ __launch_bounds__(512, 1) void expert_kernel(
    const int* __restrict__ x, const float* __restrict__ cemb,
    const float* __restrict__ We1, const float* __restrict__ be1,
    const float* __restrict__ We2, const float* __restrict__ be2,
    const int* __restrict__ action, float* __restrict__ out) {
  __shared__ __align__(16) ushort sW1[32 * 512];   // 8 ct x 4 kt frag blocks, 32 KB
  __shared__ __align__(16) ushort sW2[16 * 512];   // 4 ot x 4 kt frag blocks, 16 KB
  __shared__ __align__(16) ushort sCt[8][4 * 512]; // per-wave A tiles, 32 KB
  __shared__ __align__(16) ushort sHt[8][4 * 512]; // per-wave h tiles, 32 KB
  __shared__ __align__(16) float sbe1[NH];
  __shared__ __align__(16) float sbe2[NIW];
  __shared__ int sList[P2_R];
  __shared__ int sCount;

  const int tid = threadIdx.x;
  const int a = blockIdx.x % NA;
  const int chunk = blockIdx.x / NA;
  const int rowBeg = chunk * P2_R;
  const int rowEnd = (rowBeg + P2_R < B_N) ? rowBeg + P2_R : B_N;

  if (tid == 0) sCount = 0;
  __syncthreads();

  for (int r = rowBeg + tid; r < rowEnd; r += 512)
    if (action[r] == a) sList[atomicAdd(&sCount, 1)] = r;

  {
    const float* W1g = We1 + (size_t)a * D2 * NH;
    const int n = tid & 127, q = tid >> 7;
    const int fb = (n >> 4) * 4 + q;
    const int c16 = n & 15;
#pragma unroll
    for (int grp = 0; grp < 4; grp++) {
      short8 pk;
#pragma unroll
      for (int j = 0; j < 8; j++) {
        const int k = 32 * q + 8 * grp + j;
        pk[j] = (short)f2bf(W1g[k * NH + n]);
      }
      *(short8*)&sW1[fb * 512 + (c16 + 16 * grp) * 8] = pk;
    }
    if (tid < NH) sbe1[tid] = be1[a * NH + tid];
    if (tid < NIW) sbe2[tid] = be2[a * NIW + tid];
  }
  {
    const float* W2g = We2 + (size_t)a * NH * NIW;
    const int o = tid & 63, hq = tid >> 6;  // hq 0..7
    const int fb = (o >> 4) * 4 + (hq >> 1);
    const int c16 = o & 15;
#pragma unroll
    for (int g2 = 0; g2 < 2; g2++) {
      const int grp = (hq & 1) * 2 + g2;
      short8 pk;
#pragma unroll
      for (int j = 0; j < 8; j++) {
        const int h = 16 * hq + 8 * g2 + j;
        pk[j] = (short)f2bf(W2g[h * NIW + o]);
      }
      *(short8*)&sW2[fb * 512 + (c16 + 16 * grp) * 8] = pk;
    }
  }
  __syncthreads();

  const int cnt = sCount;
  if (cnt == 0) return;

  const int wave = tid >> 6, lane = tid & 63;
  const int rowb = (lane >> 4) * 4;
  ushort* myCt = sCt[wave];
  ushort* myHt = sHt[wave];

#pragma unroll 1
  for (int t16 = wave * 16; t16 < cnt; t16 += 128) {
    {
      const int rt = lane >> 2, q = lane & 3;
      int li = t16 + rt;
      const int g = sList[(li < cnt) ? li : 0];
      const int xi = x[2 * g + (q >> 1)];
      const float4* src = (const float4*)(cemb + (size_t)xi * NIC + (q & 1) * 32);
#pragma unroll
      for (int grp = 0; grp < 4; grp++) {
        const float4 aa = src[2 * grp], bb = src[2 * grp + 1];
        short8 pk;
        pk[0] = (short)f2bf(aa.x); pk[1] = (short)f2bf(aa.y);
        pk[2] = (short)f2bf(aa.z); pk[3] = (short)f2bf(aa.w);
        pk[4] = (short)f2bf(bb.x); pk[5] = (short)f2bf(bb.y);
        pk[6] = (short)f2bf(bb.z); pk[7] = (short)f2bf(bb.w);
        *(short8*)&myCt[q * 512 + (rt + 16 * grp) * 8] = pk;
      }
    }

    short8 A[4];
#pragma unroll
    for (int kt = 0; kt < 4; kt++) A[kt] = *(const short8*)&myCt[kt * 512 + lane * 8];
#pragma unroll
    for (int ct = 0; ct < 8; ct++) {
      const int n = ct * 16 + (lane & 15);
      const float bv = sbe1[n];
      f32x4 acc = {bv, bv, bv, bv};
#pragma unroll
      for (int kt = 0; kt < 4; kt++) {
        const short8 Bf = *(const short8*)&sW1[(ct * 4 + kt) * 512 + lane * 8];
        acc = __builtin_amdgcn_mfma_f32_16x16x32_bf16(A[kt], Bf, acc, 0, 0, 0);
      }
      const int kt2 = n >> 5, grp2 = (n & 31) >> 3, j2 = n & 7;
#pragma unroll
      for (int r = 0; r < 4; r++) {
        const float hv = fmaxf(acc[r], 0.0f);
        myHt[kt2 * 512 + ((rowb + r) + 16 * grp2) * 8 + j2] = f2bf(hv);
      }
    }

    short8 A2[4];
#pragma unroll
    for (int kt = 0; kt < 4; kt++) A2[kt] = *(const short8*)&myHt[kt * 512 + lane * 8];
    int gr4[4];
#pragma unroll
    for (int r = 0; r < 4; r++) {
      const int li2 = t16 + rowb + r;
      gr4[r] = (li2 < cnt) ? sList[li2] : -1;
    }
#pragma unroll
    for (int ot = 0; ot < 4; ot++) {
      const int o = ot * 16 + (lane & 15);
      const float bv = sbe2[o];
      f32x4 o4 = {bv, bv, bv, bv};
#pragma unroll
      for (int kt = 0; kt < 4; kt++) {
        const short8 Bf = *(const short8*)&sW2[(ot * 4 + kt) * 512 + lane * 8];
        o4 = __builtin_amdgcn_mfma_f32_16x16x32_bf16(A2[kt], Bf, o4, 0, 0, 0);
      }
#pragma unroll
      for (int r = 0; r < 4; r++) {
        if (gr4[r] >= 0) out[(size_t)gr4[r] * NIW + o] = o4[r];
      }
    }
  }
}

extern "C" void kernel_launch(void* const* d_in, const int* in_sizes, int n_in,
                              void* d_out, int out_size, void* d_ws, size_t ws_size,
                              hipStream_t stream) {
  const int*   x    = (const int*)d_in[0];
  const int*   y    = (const int*)d_in[1];
  const float* cemb = (const float*)d_in[2];
  const float* wemb = (const float*)d_in[3];
  const float* Wp1  = (const float*)d_in[4];
  const float* bp1  = (const float*)d_in[5];
  const float* Wp2  = (const float*)d_in[6];
  const float* bp2  = (const float*)d_in[7];
  const float* We1  = (const float*)d_in[8];
  const float* be1  = (const float*)d_in[9];
  const float* We2  = (const float*)d_in[10];
  const float* be2  = (const float*)d_in[11];

  float* out      = (float*)d_out;
  float* out_wemb = out + (size_t)B_N * NIW;
  int*   action   = (int*)d_ws;   // B_N ints

  policy_kernel<<<B_N / 128, 512, 0, stream>>>(
      x, y, cemb, wemb, Wp1, bp1, Wp2, bp2, out_wemb, action);
  expert_kernel<<<NA * P2_NCHUNK, 512, 0, stream>>>(
      x, cemb, We1, be1, We2, be2, action, out);
}